// Round 1
// baseline (449.730 us; speedup 1.0000x reference)
//
#include <hip/hip_runtime.h>

#define BATCH 8
#define INC 512
#define CM 512
#define CN 128
#define NPIX 4096
#define NSPLIT 8
#define LDSP 68   // padded row stride (floats): keeps 16B alignment, breaks store conflicts

// 4x4 micro-tile inner product over a 16-deep K chunk.
#define TILE_INNER(As, Bs, acc, ty, tx)                                          \
  _Pragma("unroll")                                                              \
  for (int cc = 0; cc < 16; ++cc) {                                              \
    float a0 = As[cc][(ty)*4+0], a1 = As[cc][(ty)*4+1],                          \
          a2 = As[cc][(ty)*4+2], a3 = As[cc][(ty)*4+3];                          \
    float b0 = Bs[cc][(tx)*4+0], b1 = Bs[cc][(tx)*4+1],                          \
          b2 = Bs[cc][(tx)*4+2], b3 = Bs[cc][(tx)*4+3];                          \
    acc[0][0] += a0*b0; acc[0][1] += a0*b1; acc[0][2] += a0*b2; acc[0][3] += a0*b3; \
    acc[1][0] += a1*b0; acc[1][1] += a1*b1; acc[1][2] += a1*b2; acc[1][3] += a1*b3; \
    acc[2][0] += a2*b0; acc[2][1] += a2*b1; acc[2][2] += a2*b2; acc[2][3] += a2*b3; \
    acc[3][0] += a3*b0; acc[3][1] += a3*b1; acc[3][2] += a3*b2; acc[3][3] += a3*b3; \
  }

#define STORE_T(S, col, row, v4)                                                 \
  S[(col)+0][row] = v4.x; S[(col)+1][row] = v4.y;                                \
  S[(col)+2][row] = v4.z; S[(col)+3][row] = v4.w;

// K1: Bf = wB@x + bB, V = wV@x + bV.  grid (NPIX/64, CN/64, BATCH*2)
__global__ __launch_bounds__(256) void k_proj(
    const float* __restrict__ x,
    const float* __restrict__ wB, const float* __restrict__ bB,
    const float* __restrict__ wV, const float* __restrict__ bV,
    float* __restrict__ Bbuf, float* __restrict__ Vbuf)
{
    int tid = threadIdx.x;
    int n0 = blockIdx.x * 64;
    int k0 = blockIdx.y * 64;
    int z  = blockIdx.z;
    int b  = z >> 1;
    const float* W    = (z & 1) ? wV : wB;
    const float* bias = (z & 1) ? bV : bB;
    float* out        = (z & 1) ? Vbuf : Bbuf;

    __shared__ float As[16][LDSP];  // [c_chunk][k]
    __shared__ float Bs[16][LDSP];  // [c_chunk][n]

    float acc[4][4] = {};
    int ty = tid >> 4, tx = tid & 15;
    int wrow = tid >> 2,  wcol = (tid & 3) * 4;    // weight: transpose-stage
    int xrow = tid >> 4,  xcol = (tid & 15) * 4;   // x: direct stage

    const float* xb = x + (size_t)b * INC * NPIX;

    for (int c0 = 0; c0 < INC; c0 += 16) {
        __syncthreads();
        float4 w4 = *(const float4*)&W[(size_t)(k0 + wrow) * INC + c0 + wcol];
        STORE_T(As, wcol, wrow, w4);
        float4 x4 = *(const float4*)&xb[(size_t)(c0 + xrow) * NPIX + n0 + xcol];
        *(float4*)&Bs[xrow][xcol] = x4;
        __syncthreads();
        TILE_INNER(As, Bs, acc, ty, tx);
    }

    #pragma unroll
    for (int i = 0; i < 4; ++i) {
        int k = k0 + ty * 4 + i;
        float bi = bias[k];
        float4 o;
        o.x = acc[i][0] + bi; o.y = acc[i][1] + bi;
        o.z = acc[i][2] + bi; o.w = acc[i][3] + bi;
        *(float4*)&out[((size_t)b * CN + k) * NPIX + n0 + tx * 4] = o;
    }
}

// K2: in-place softmax over N per (b,k) row. grid (BATCH*CN), 256 thr.
__global__ __launch_bounds__(256) void k_softmax_rows(float* __restrict__ buf)
{
    int row = blockIdx.x;
    float* p = buf + (size_t)row * NPIX;
    int tid = threadIdx.x;

    float4 v[4];
    #pragma unroll
    for (int i = 0; i < 4; ++i) v[i] = *(float4*)&p[(i * 256 + tid) * 4];

    float m = -1e30f;
    #pragma unroll
    for (int i = 0; i < 4; ++i) {
        m = fmaxf(m, fmaxf(fmaxf(v[i].x, v[i].y), fmaxf(v[i].z, v[i].w)));
    }
    for (int o = 32; o > 0; o >>= 1) m = fmaxf(m, __shfl_xor(m, o));
    __shared__ float smax[4];
    __shared__ float ssum[4];
    if ((tid & 63) == 0) smax[tid >> 6] = m;
    __syncthreads();
    m = fmaxf(fmaxf(smax[0], smax[1]), fmaxf(smax[2], smax[3]));

    float s = 0.f;
    #pragma unroll
    for (int i = 0; i < 4; ++i) {
        v[i].x = __expf(v[i].x - m); v[i].y = __expf(v[i].y - m);
        v[i].z = __expf(v[i].z - m); v[i].w = __expf(v[i].w - m);
        s += v[i].x + v[i].y + v[i].z + v[i].w;
    }
    for (int o = 32; o > 0; o >>= 1) s += __shfl_xor(s, o);
    if ((tid & 63) == 0) ssum[tid >> 6] = s;
    __syncthreads();
    s = ssum[0] + ssum[1] + ssum[2] + ssum[3];
    float r = 1.0f / s;
    #pragma unroll
    for (int i = 0; i < 4; ++i) {
        v[i].x *= r; v[i].y *= r; v[i].z *= r; v[i].w *= r;
        *(float4*)&p[(i * 256 + tid) * 4] = v[i];
    }
}

// K3: in-place softmax over CN per (b,n) pixel. grid (BATCH*NPIX/256), 256 thr.
__global__ __launch_bounds__(256) void k_softmax_cols(float* __restrict__ buf)
{
    int g = blockIdx.x * 256 + threadIdx.x;   // 0..32767
    int b = g >> 12, n = g & (NPIX - 1);
    float* p = buf + (size_t)b * CN * NPIX + n;
    float m = -1e30f, l = 0.f;
    for (int k = 0; k < CN; ++k) {
        float v = p[(size_t)k * NPIX];
        float nm = fmaxf(m, v);
        l = l * __expf(m - nm) + __expf(v - nm);
        m = nm;
    }
    float r = 1.0f / l;
    for (int k = 0; k < CN; ++k) {
        float v = p[(size_t)k * NPIX];
        p[(size_t)k * NPIX] = __expf(v - m) * r;
    }
}

// K4a: P[c,k] += sum_n x[c,n]*softB[k,n], n-split with atomics.
// grid (CN/64, INC/64, BATCH*NSPLIT)
__global__ __launch_bounds__(256) void k_gather_P(
    const float* __restrict__ x, const float* __restrict__ sB,
    float* __restrict__ P)
{
    int tid = threadIdx.x;
    int k0 = blockIdx.x * 64;
    int c0 = blockIdx.y * 64;
    int z = blockIdx.z;
    int b = z / NSPLIT, ns = z % NSPLIT;
    int nbeg = ns * (NPIX / NSPLIT);

    __shared__ float As[16][LDSP];  // [n_chunk][c]
    __shared__ float Bs[16][LDSP];  // [n_chunk][k]

    float acc[4][4] = {};
    int ty = tid >> 4, tx = tid & 15;
    int row = tid >> 2, colb = (tid & 3) * 4;

    const float* xb = x  + (size_t)b * INC * NPIX;
    const float* sb = sB + (size_t)b * CN * NPIX;

    for (int n0 = nbeg; n0 < nbeg + NPIX / NSPLIT; n0 += 16) {
        __syncthreads();
        float4 a4 = *(const float4*)&xb[(size_t)(c0 + row) * NPIX + n0 + colb];
        STORE_T(As, colb, row, a4);
        float4 b4 = *(const float4*)&sb[(size_t)(k0 + row) * NPIX + n0 + colb];
        STORE_T(Bs, colb, row, b4);
        __syncthreads();
        TILE_INNER(As, Bs, acc, ty, tx);
    }

    #pragma unroll
    for (int i = 0; i < 4; ++i)
        #pragma unroll
        for (int j = 0; j < 4; ++j)
            atomicAdd(&P[((size_t)b * INC + c0 + ty * 4 + i) * CN + k0 + tx * 4 + j],
                      acc[i][j]);
}

// K4b: G = wA @ P + bA.  grid (CN/64, CM/64, BATCH)
__global__ __launch_bounds__(256) void k_G(
    const float* __restrict__ wA, const float* __restrict__ bA,
    const float* __restrict__ P, float* __restrict__ G)
{
    int tid = threadIdx.x;
    int k0 = blockIdx.x * 64;
    int m0 = blockIdx.y * 64;
    int b  = blockIdx.z;

    __shared__ float As[16][LDSP];  // [c_chunk][m]
    __shared__ float Bs[16][LDSP];  // [c_chunk][k]

    float acc[4][4] = {};
    int ty = tid >> 4, tx = tid & 15;
    int wrow = tid >> 2,  wcol = (tid & 3) * 4;
    int xrow = tid >> 4,  xcol = (tid & 15) * 4;

    for (int c0 = 0; c0 < INC; c0 += 16) {
        __syncthreads();
        float4 w4 = *(const float4*)&wA[(size_t)(m0 + wrow) * INC + c0 + wcol];
        STORE_T(As, wcol, wrow, w4);
        float4 p4 = *(const float4*)&P[((size_t)b * INC + c0 + xrow) * CN + k0 + xcol];
        *(float4*)&Bs[xrow][xcol] = p4;
        __syncthreads();
        TILE_INNER(As, Bs, acc, ty, tx);
    }

    #pragma unroll
    for (int i = 0; i < 4; ++i) {
        int m = m0 + ty * 4 + i;
        float bi = bA[m];
        float4 o;
        o.x = acc[i][0] + bi; o.y = acc[i][1] + bi;
        o.z = acc[i][2] + bi; o.w = acc[i][3] + bi;
        *(float4*)&G[((size_t)b * CM + m) * CN + k0 + tx * 4] = o;
    }
}

// K5: out = G @ softV + y.  grid (NPIX/64, CM/64, BATCH)
__global__ __launch_bounds__(256) void k_Z(
    const float* __restrict__ G, const float* __restrict__ sV,
    const float* __restrict__ y, float* __restrict__ out)
{
    int tid = threadIdx.x;
    int n0 = blockIdx.x * 64;
    int m0 = blockIdx.y * 64;
    int b  = blockIdx.z;

    __shared__ float As[16][LDSP];  // [k_chunk][m]
    __shared__ float Bs[16][LDSP];  // [k_chunk][n]

    float acc[4][4] = {};
    int ty = tid >> 4, tx = tid & 15;
    int wrow = tid >> 2,  wcol = (tid & 3) * 4;
    int xrow = tid >> 4,  xcol = (tid & 15) * 4;

    for (int kc = 0; kc < CN; kc += 16) {
        __syncthreads();
        float4 g4 = *(const float4*)&G[((size_t)b * CM + m0 + wrow) * CN + kc + wcol];
        STORE_T(As, wcol, wrow, g4);
        float4 v4 = *(const float4*)&sV[((size_t)b * CN + kc + xrow) * NPIX + n0 + xcol];
        *(float4*)&Bs[xrow][xcol] = v4;
        __syncthreads();
        TILE_INNER(As, Bs, acc, ty, tx);
    }

    #pragma unroll
    for (int i = 0; i < 4; ++i) {
        size_t idx = ((size_t)b * CM + m0 + ty * 4 + i) * NPIX + n0 + tx * 4;
        float4 y4 = *(const float4*)&y[idx];
        float4 o;
        o.x = acc[i][0] + y4.x; o.y = acc[i][1] + y4.y;
        o.z = acc[i][2] + y4.z; o.w = acc[i][3] + y4.w;
        *(float4*)&out[idx] = o;
    }
}

extern "C" void kernel_launch(void* const* d_in, const int* in_sizes, int n_in,
                              void* d_out, int out_size, void* d_ws, size_t ws_size,
                              hipStream_t stream)
{
    const float* x  = (const float*)d_in[0];
    const float* y  = (const float*)d_in[1];
    const float* wA = (const float*)d_in[2];
    const float* bA = (const float*)d_in[3];
    const float* wB = (const float*)d_in[4];
    const float* bB = (const float*)d_in[5];
    const float* wV = (const float*)d_in[6];
    const float* bV = (const float*)d_in[7];
    float* out = (float*)d_out;

    float* Bbuf = (float*)d_ws;                                  // [B, CN, N]
    float* Vbuf = Bbuf + (size_t)BATCH * CN * NPIX;              // [B, CN, N]
    float* Pbuf = Vbuf + (size_t)BATCH * CN * NPIX;              // [B, INC, CN]
    float* Gbuf = Pbuf + (size_t)BATCH * INC * CN;               // [B, CM, CN]

    hipMemsetAsync(Pbuf, 0, (size_t)BATCH * INC * CN * sizeof(float), stream);

    k_proj<<<dim3(NPIX / 64, CN / 64, BATCH * 2), 256, 0, stream>>>(
        x, wB, bB, wV, bV, Bbuf, Vbuf);
    k_softmax_rows<<<dim3(BATCH * CN), 256, 0, stream>>>(Bbuf);
    k_softmax_cols<<<dim3(BATCH * NPIX / 256), 256, 0, stream>>>(Vbuf);
    k_gather_P<<<dim3(CN / 64, INC / 64, BATCH * NSPLIT), 256, 0, stream>>>(
        x, Bbuf, Pbuf);
    k_G<<<dim3(CN / 64, CM / 64, BATCH), 256, 0, stream>>>(wA, bA, Pbuf, Gbuf);
    k_Z<<<dim3(NPIX / 64, CM / 64, BATCH), 256, 0, stream>>>(Gbuf, Vbuf, y, out);
}

// Round 2
// 272.950 us; speedup vs baseline: 1.6477x; 1.6477x over previous
//
#include <hip/hip_runtime.h>

#define BATCH 8
#define INC 512
#define CM 512
#define CN 128
#define NPIX 4096
#define NSPLIT 16

typedef short bf16x8 __attribute__((ext_vector_type(8)));
typedef float f32x4 __attribute__((ext_vector_type(4)));
typedef unsigned short us8v __attribute__((ext_vector_type(8)));

__device__ __forceinline__ unsigned short f2b(float f) {
    union { float f; unsigned u; } v; v.f = f;
    unsigned r = v.u + 0x7FFF + ((v.u >> 16) & 1);
    return (unsigned short)(r >> 16);
}
__device__ __forceinline__ float b2f(unsigned short u) {
    union { unsigned u; float f; } v; v.u = ((unsigned)u) << 16;
    return v.f;
}

__device__ __forceinline__ void gl_lds16(const unsigned short* g, unsigned short* l) {
    __builtin_amdgcn_global_load_lds(
        (const __attribute__((address_space(1))) unsigned int*)g,
        (__attribute__((address_space(3))) unsigned int*)l, 16, 0, 0);
}

// Stage a [128 rows][32 bf16] tile (8KB) from row-major src (ld elems/row) at
// column kbase into LDS, 16B/lane, 2 issues/thread. LDS layout: row-major, 64B rows.
__device__ __forceinline__ void stage_tile(const unsigned short* src, int ld, int kbase,
                                           unsigned short* lds, int t) {
    #pragma unroll
    for (int q = 0; q < 2; ++q) {
        int f = q * 256 + t;
        const unsigned short* g = src + (size_t)(f >> 2) * ld + kbase + (f & 3) * 8;
        gl_lds16(g, lds + f * 8);
    }
}

// 4 waves, wave (wr,wc) owns 64x64; 16 MFMAs per BK=32 step.
__device__ __forceinline__ void bt_compute(const unsigned short* lA, const unsigned short* lB,
                                           f32x4 acc[4][4], int wr, int wc, int lane) {
    int lr = lane & 15, lq = lane >> 4;
    bf16x8 av[4], bv[4];
    #pragma unroll
    for (int i = 0; i < 4; ++i)
        av[i] = *(const bf16x8*)&lA[(wr * 64 + i * 16 + lr) * 32 + lq * 8];
    #pragma unroll
    for (int j = 0; j < 4; ++j)
        bv[j] = *(const bf16x8*)&lB[(wc * 64 + j * 16 + lr) * 32 + lq * 8];
    #pragma unroll
    for (int i = 0; i < 4; ++i)
        #pragma unroll
        for (int j = 0; j < 4; ++j)
            acc[i][j] = __builtin_amdgcn_mfma_f32_16x16x32_bf16(av[i], bv[j], acc[i][j], 0, 0, 0);
}

#define ZERO_ACC(acc)                       \
    f32x4 acc[4][4];                        \
    {                                       \
        f32x4 z4 = {0.f, 0.f, 0.f, 0.f};   \
        for (int i = 0; i < 4; ++i)         \
            for (int j = 0; j < 4; ++j)     \
                acc[i][j] = z4;             \
    }

// K0a: weights fp32 -> bf16 (wA 512x512, wB 128x512, wV 128x512)
__global__ __launch_bounds__(256) void k_prep_w(
    const float* __restrict__ wA, const float* __restrict__ wB, const float* __restrict__ wV,
    unsigned short* __restrict__ wA16, unsigned short* __restrict__ wB16,
    unsigned short* __restrict__ wV16)
{
    int e = (blockIdx.x * 256 + threadIdx.x) * 4;
    const float* src; unsigned short* dst; int off;
    if (e < 262144)       { src = wA; dst = wA16; off = e; }
    else if (e < 327680)  { src = wB; dst = wB16; off = e - 262144; }
    else                  { src = wV; dst = wV16; off = e - 327680; }
    float4 v = *(const float4*)&src[off];
    ushort4 u = make_ushort4(f2b(v.x), f2b(v.y), f2b(v.z), f2b(v.w));
    *(ushort4*)&dst[off] = u;
}

// K0b: xT16[b][n][c] = bf16(x[b][c][n]).  grid (NPIX/64, INC/64, B)
__global__ __launch_bounds__(256) void k_transpose(
    const float* __restrict__ x, unsigned short* __restrict__ xT)
{
    __shared__ unsigned short tile[64][68];
    int n0 = blockIdx.x * 64, c0 = blockIdx.y * 64, b = blockIdx.z;
    int t = threadIdx.x;
    int tr = t >> 4, tc4 = (t & 15) * 4;
    const float* xb = x + ((size_t)b * INC + c0) * NPIX + n0;
    #pragma unroll
    for (int p = 0; p < 4; ++p) {
        int r = p * 16 + tr;
        float4 v = *(const float4*)&xb[(size_t)r * NPIX + tc4];
        tile[r][tc4 + 0] = f2b(v.x); tile[r][tc4 + 1] = f2b(v.y);
        tile[r][tc4 + 2] = f2b(v.z); tile[r][tc4 + 3] = f2b(v.w);
    }
    __syncthreads();
    unsigned short* o = xT + ((size_t)b * NPIX + n0) * INC + c0;
    #pragma unroll
    for (int p = 0; p < 4; ++p) {
        int n = p * 16 + tr;
        ushort4 u = make_ushort4(tile[tc4 + 0][n], tile[tc4 + 1][n],
                                 tile[tc4 + 2][n], tile[tc4 + 3][n]);
        *(ushort4*)&o[(size_t)n * INC + tc4] = u;
    }
}

// K1: Bf16/V16 [b][k][n] = bf16(W @ x + 0) (bias added here).  grid (NPIX/128, B*2)
__global__ __launch_bounds__(256) void k_proj(
    const unsigned short* __restrict__ xT, const unsigned short* __restrict__ wB16,
    const unsigned short* __restrict__ wV16, const float* __restrict__ bB,
    const float* __restrict__ bV, unsigned short* __restrict__ Bf16,
    unsigned short* __restrict__ V16)
{
    __shared__ unsigned short lA[128 * 32], lB[128 * 32];
    int t = threadIdx.x;
    int n0 = blockIdx.x * 128;
    int z = blockIdx.y, b = z >> 1, br = z & 1;
    const unsigned short* A = br ? wV16 : wB16;
    const float* bias = br ? bV : bB;
    unsigned short* out = br ? V16 : Bf16;
    const unsigned short* Bm = xT + ((size_t)b * NPIX + n0) * INC;

    ZERO_ACC(acc);
    int lane = t & 63, w = t >> 6, wr = w >> 1, wc = w & 1;

    for (int c = 0; c < INC; c += 32) {
        stage_tile(A, INC, c, lA, t);
        stage_tile(Bm, INC, c, lB, t);
        __syncthreads();
        bt_compute(lA, lB, acc, wr, wc, lane);
        __syncthreads();
    }
    int lr = lane & 15, lq = lane >> 4;
    #pragma unroll
    for (int i = 0; i < 4; ++i)
        #pragma unroll
        for (int reg = 0; reg < 4; ++reg) {
            int k = wr * 64 + i * 16 + lq * 4 + reg;
            float bv_ = bias[k];
            #pragma unroll
            for (int j = 0; j < 4; ++j) {
                int n = n0 + wc * 64 + j * 16 + lr;
                out[((size_t)b * CN + k) * NPIX + n] = f2b(acc[i][j][reg] + bv_);
            }
        }
}

// K2: sB[b][k][n] = softmax over n of Bf16.  grid (B*CN), 256 thr.
__global__ __launch_bounds__(256) void k_softmax_rows(
    const unsigned short* __restrict__ Bf16, unsigned short* __restrict__ sB)
{
    __shared__ float red[8];
    int row = blockIdx.x, t = threadIdx.x;
    const unsigned short* p = Bf16 + (size_t)row * NPIX + t * 16;
    us8v u0 = *(const us8v*)p, u1 = *(const us8v*)(p + 8);
    float v[16];
    #pragma unroll
    for (int j = 0; j < 8; ++j) { v[j] = b2f(u0[j]); v[8 + j] = b2f(u1[j]); }
    float m = -1e30f;
    #pragma unroll
    for (int j = 0; j < 16; ++j) m = fmaxf(m, v[j]);
    for (int o = 32; o > 0; o >>= 1) m = fmaxf(m, __shfl_xor(m, o));
    if ((t & 63) == 0) red[t >> 6] = m;
    __syncthreads();
    m = fmaxf(fmaxf(red[0], red[1]), fmaxf(red[2], red[3]));
    float s = 0.f;
    #pragma unroll
    for (int j = 0; j < 16; ++j) { v[j] = __expf(v[j] - m); s += v[j]; }
    for (int o = 32; o > 0; o >>= 1) s += __shfl_xor(s, o);
    if ((t & 63) == 0) red[4 + (t >> 6)] = s;
    __syncthreads();
    float r = 1.0f / (red[4] + red[5] + red[6] + red[7]);
    us8v o0, o1;
    #pragma unroll
    for (int j = 0; j < 8; ++j) { o0[j] = f2b(v[j] * r); o1[j] = f2b(v[8 + j] * r); }
    unsigned short* q = sB + (size_t)row * NPIX + t * 16;
    *(us8v*)q = o0; *(us8v*)(q + 8) = o1;
}

// K3: sVt[b][n][k] = softmax over k of V16[b][k][n], transposed out. grid (NPIX/128, B)
__global__ __launch_bounds__(256) void k_softmax_cols(
    const unsigned short* __restrict__ V16, unsigned short* __restrict__ sVt)
{
    __shared__ unsigned short tv[128][138];
    __shared__ float sm[128], sr[128];
    int n0 = blockIdx.x * 128, b = blockIdx.y, t = threadIdx.x;
    const unsigned short* vb = V16 + (size_t)b * CN * NPIX;
    #pragma unroll 4
    for (int it = 0; it < 64; ++it) {
        int idx = it * 256 + t, k = idx >> 7, nl = idx & 127;
        tv[nl][k] = vb[(size_t)k * NPIX + n0 + nl];
    }
    __syncthreads();
    if (t < 128) {
        float m = -1e30f;
        for (int k = 0; k < 128; ++k) m = fmaxf(m, b2f(tv[t][k]));
        float s = 0.f;
        for (int k = 0; k < 128; ++k) s += __expf(b2f(tv[t][k]) - m);
        sm[t] = m; sr[t] = 1.0f / s;
    }
    __syncthreads();
    unsigned short* ob = sVt + ((size_t)b * NPIX + n0) * CN;
    #pragma unroll
    for (int it = 0; it < 8; ++it) {
        int idx = it * 2048 + t * 8, nl = idx >> 7, k0 = idx & 127;
        float m = sm[nl], r = sr[nl];
        us8v o;
        #pragma unroll
        for (int j = 0; j < 8; ++j) o[j] = f2b(__expf(b2f(tv[nl][k0 + j]) - m) * r);
        *(us8v*)&ob[(size_t)nl * CN + k0] = o;
    }
}

// K4: Pts[s][b][k][c] = sum_{n in split s} sB[k][n] * x[c][n].  grid (INC/128, NSPLIT, B)
__global__ __launch_bounds__(256) void k_gather(
    const float* __restrict__ x, const unsigned short* __restrict__ sB,
    float* __restrict__ Pts)
{
    __shared__ unsigned short lA[128 * 32], lB[128 * 32];
    int t = threadIdx.x;
    int c0 = blockIdx.x * 128, s = blockIdx.y, b = blockIdx.z;
    const unsigned short* A = sB + (size_t)b * CN * NPIX;
    const float* xb = x + ((size_t)b * INC + c0) * NPIX;
    int nbase = s * (NPIX / NSPLIT);

    ZERO_ACC(acc);
    int lane = t & 63, w = t >> 6, wr = w >> 1, wc = w & 1;

    for (int it = 0; it < (NPIX / NSPLIT) / 32; ++it) {
        int nb = nbase + it * 32;
        stage_tile(A, NPIX, nb, lA, t);
        #pragma unroll
        for (int q = 0; q < 4; ++q) {
            int f = q * 256 + t, r = f >> 3, nof = (f & 7) * 4;
            float4 v = *(const float4*)&xb[(size_t)r * NPIX + nb + nof];
            ushort4 u = make_ushort4(f2b(v.x), f2b(v.y), f2b(v.z), f2b(v.w));
            *(ushort4*)&lB[r * 32 + nof] = u;
        }
        __syncthreads();
        bt_compute(lA, lB, acc, wr, wc, lane);
        __syncthreads();
    }
    int lr = lane & 15, lq = lane >> 4;
    #pragma unroll
    for (int i = 0; i < 4; ++i)
        #pragma unroll
        for (int reg = 0; reg < 4; ++reg) {
            int k = wr * 64 + i * 16 + lq * 4 + reg;
            #pragma unroll
            for (int j = 0; j < 4; ++j) {
                int cc = wc * 64 + j * 16 + lr;
                Pts[(((size_t)s * BATCH + b) * CN + k) * INC + c0 + cc] = acc[i][j][reg];
            }
        }
}

// K5: Pt16[b][k][c] = bf16(sum_s Pts).  grid 512, 256 thr.
__global__ __launch_bounds__(256) void k_reduceP(
    const float* __restrict__ Pts, unsigned short* __restrict__ Pt16)
{
    int base = (blockIdx.x * 256 + threadIdx.x) * 4;
    float4 sacc = make_float4(0.f, 0.f, 0.f, 0.f);
    #pragma unroll
    for (int sp = 0; sp < NSPLIT; ++sp) {
        float4 v = *(const float4*)&Pts[(size_t)sp * (BATCH * CN * INC) + base];
        sacc.x += v.x; sacc.y += v.y; sacc.z += v.z; sacc.w += v.w;
    }
    *(ushort4*)&Pt16[base] = make_ushort4(f2b(sacc.x), f2b(sacc.y), f2b(sacc.z), f2b(sacc.w));
}

// K6: G16[b][m][k] = bf16(wA @ P + bA).  grid (CM/128, B)
__global__ __launch_bounds__(256) void k_G(
    const unsigned short* __restrict__ wA16, const float* __restrict__ bA,
    const unsigned short* __restrict__ Pt16, unsigned short* __restrict__ G16)
{
    __shared__ unsigned short lA[128 * 32], lB[128 * 32];
    int t = threadIdx.x;
    int m0 = blockIdx.x * 128, b = blockIdx.y;
    const unsigned short* A = wA16 + (size_t)m0 * INC;
    const unsigned short* Bm = Pt16 + (size_t)b * CN * INC;

    ZERO_ACC(acc);
    int lane = t & 63, w = t >> 6, wr = w >> 1, wc = w & 1;

    for (int c = 0; c < INC; c += 32) {
        stage_tile(A, INC, c, lA, t);
        stage_tile(Bm, INC, c, lB, t);
        __syncthreads();
        bt_compute(lA, lB, acc, wr, wc, lane);
        __syncthreads();
    }
    int lr = lane & 15, lq = lane >> 4;
    #pragma unroll
    for (int i = 0; i < 4; ++i)
        #pragma unroll
        for (int reg = 0; reg < 4; ++reg) {
            int m = m0 + wr * 64 + i * 16 + lq * 4 + reg;
            float bv_ = bA[m];
            #pragma unroll
            for (int j = 0; j < 4; ++j) {
                int kc = wc * 64 + j * 16 + lr;
                G16[((size_t)b * CM + m) * CN + kc] = f2b(acc[i][j][reg] + bv_);
            }
        }
}

// K7: out[b][m][n] = G @ sV + y.  grid (NPIX/128, CM/128, B)
__global__ __launch_bounds__(256) void k_Z(
    const unsigned short* __restrict__ G16, const unsigned short* __restrict__ sVt,
    const float* __restrict__ y, float* __restrict__ out)
{
    __shared__ unsigned short lA[128 * 32], lB[128 * 32];
    int t = threadIdx.x;
    int n0 = blockIdx.x * 128, m0 = blockIdx.y * 128, b = blockIdx.z;
    const unsigned short* A = G16 + ((size_t)b * CM + m0) * CN;
    const unsigned short* Bm = sVt + ((size_t)b * NPIX + n0) * CN;

    ZERO_ACC(acc);
    int lane = t & 63, w = t >> 6, wr = w >> 1, wc = w & 1;

    for (int kc = 0; kc < CN; kc += 32) {
        stage_tile(A, CN, kc, lA, t);
        stage_tile(Bm, CN, kc, lB, t);
        __syncthreads();
        bt_compute(lA, lB, acc, wr, wc, lane);
        __syncthreads();
    }
    int lr = lane & 15, lq = lane >> 4;
    #pragma unroll
    for (int i = 0; i < 4; ++i)
        #pragma unroll
        for (int reg = 0; reg < 4; ++reg) {
            int m = m0 + wr * 64 + i * 16 + lq * 4 + reg;
            #pragma unroll
            for (int j = 0; j < 4; ++j) {
                int n = n0 + wc * 64 + j * 16 + lr;
                size_t idx = ((size_t)b * CM + m) * NPIX + n;
                out[idx] = acc[i][j][reg] + y[idx];
            }
        }
}

extern "C" void kernel_launch(void* const* d_in, const int* in_sizes, int n_in,
                              void* d_out, int out_size, void* d_ws, size_t ws_size,
                              hipStream_t stream)
{
    const float* x  = (const float*)d_in[0];
    const float* y  = (const float*)d_in[1];
    const float* wA = (const float*)d_in[2];
    const float* bA = (const float*)d_in[3];
    const float* wB = (const float*)d_in[4];
    const float* bB = (const float*)d_in[5];
    const float* wV = (const float*)d_in[6];
    const float* bV = (const float*)d_in[7];
    float* out = (float*)d_out;

    unsigned short* xT16 = (unsigned short*)d_ws;            // 16,777,216
    unsigned short* wA16 = xT16 + 16777216;                  // 262,144
    unsigned short* wB16 = wA16 + 262144;                    // 65,536
    unsigned short* wV16 = wB16 + 65536;                     // 65,536
    unsigned short* Bf16 = wV16 + 65536;                     // 4,194,304
    unsigned short* V16  = Bf16 + 4194304;                   // 4,194,304
    unsigned short* sB   = V16  + 4194304;                   // 4,194,304
    unsigned short* sVt  = sB   + 4194304;                   // 4,194,304
    unsigned short* Pt16 = sVt  + 4194304;                   // 524,288
    float*  Pts = (float*)(Pt16 + 524288);                   // 16*8*128*512 f32
    unsigned short* G16  = (unsigned short*)(Pts + (size_t)NSPLIT * BATCH * CN * INC);

    k_prep_w<<<384, 256, 0, stream>>>(wA, wB, wV, wA16, wB16, wV16);
    k_transpose<<<dim3(NPIX / 64, INC / 64, BATCH), 256, 0, stream>>>(x, xT16);
    k_proj<<<dim3(NPIX / 128, BATCH * 2), 256, 0, stream>>>(xT16, wB16, wV16, bB, bV, Bf16, V16);
    k_softmax_rows<<<dim3(BATCH * CN), 256, 0, stream>>>(Bf16, sB);
    k_softmax_cols<<<dim3(NPIX / 128, BATCH), 256, 0, stream>>>(V16, sVt);
    k_gather<<<dim3(INC / 128, NSPLIT, BATCH), 256, 0, stream>>>(x, sB, Pts);
    k_reduceP<<<512, 256, 0, stream>>>(Pts, Pt16);
    k_G<<<dim3(CM / 128, BATCH), 256, 0, stream>>>(wA16, bA, Pt16, G16);
    k_Z<<<dim3(NPIX / 128, CM / 128, BATCH), 256, 0, stream>>>(G16, sVt, y, out);
}

// Round 3
// 265.554 us; speedup vs baseline: 1.6936x; 1.0279x over previous
//
#include <hip/hip_runtime.h>

#define BATCH 8
#define INC 512
#define CM 512
#define CN 128
#define NPIX 4096
#define NSPLIT 8

typedef short bf16x8 __attribute__((ext_vector_type(8)));
typedef float f32x4 __attribute__((ext_vector_type(4)));
typedef unsigned short us8v __attribute__((ext_vector_type(8)));

__device__ __forceinline__ unsigned short f2b(float f) {
    union { float f; unsigned u; } v; v.f = f;
    unsigned r = v.u + 0x7FFF + ((v.u >> 16) & 1);
    return (unsigned short)(r >> 16);
}
__device__ __forceinline__ float b2f(unsigned short u) {
    union { unsigned u; float f; } v; v.u = ((unsigned)u) << 16;
    return v.f;
}

__device__ __forceinline__ void gl_lds16(const unsigned short* g, unsigned short* l) {
    __builtin_amdgcn_global_load_lds(
        (const __attribute__((address_space(1))) unsigned int*)g,
        (__attribute__((address_space(3))) unsigned int*)l, 16, 0, 0);
}

// Stage a [128 rows][32 bf16] tile (8KB) from row-major src (ld elems/row) at
// column kbase into LDS, 16B/lane, 2 issues/thread.
__device__ __forceinline__ void stage_tile(const unsigned short* src, int ld, int kbase,
                                           unsigned short* lds, int t) {
    #pragma unroll
    for (int q = 0; q < 2; ++q) {
        int f = q * 256 + t;
        const unsigned short* g = src + (size_t)(f >> 2) * ld + kbase + (f & 3) * 8;
        gl_lds16(g, lds + f * 8);
    }
}

// 4 waves, wave (wr,wc) owns 64x64; 16 MFMAs per BK=32 step.
__device__ __forceinline__ void bt_compute(const unsigned short* lA, const unsigned short* lB,
                                           f32x4 acc[4][4], int wr, int wc, int lane) {
    int lr = lane & 15, lq = lane >> 4;
    bf16x8 av[4], bv[4];
    #pragma unroll
    for (int i = 0; i < 4; ++i)
        av[i] = *(const bf16x8*)&lA[(wr * 64 + i * 16 + lr) * 32 + lq * 8];
    #pragma unroll
    for (int j = 0; j < 4; ++j)
        bv[j] = *(const bf16x8*)&lB[(wc * 64 + j * 16 + lr) * 32 + lq * 8];
    #pragma unroll
    for (int i = 0; i < 4; ++i)
        #pragma unroll
        for (int j = 0; j < 4; ++j)
            acc[i][j] = __builtin_amdgcn_mfma_f32_16x16x32_bf16(av[i], bv[j], acc[i][j], 0, 0, 0);
}

#define ZERO_ACC(acc)                       \
    f32x4 acc[4][4];                        \
    {                                       \
        f32x4 z4 = {0.f, 0.f, 0.f, 0.f};   \
        for (int i = 0; i < 4; ++i)         \
            for (int j = 0; j < 4; ++j)     \
                acc[i][j] = z4;             \
    }

// Stage one 32-row chunk (rows [ch*32, ch*32+32) of the 128x128 C tile) to LDS
// as fp32 [32][132] (pad 132 -> lq-pairs land 16 banks apart: free 2-way).
__device__ __forceinline__ void ep_stage(float* ep, const f32x4 (*acc)[4],
                                         int ch, int wr, int wc, int lane) {
    if (wr == (ch >> 1)) {
        int lr = lane & 15, lq = lane >> 4;
        int ibase = (ch & 1) * 2;
        #pragma unroll
        for (int ii = 0; ii < 2; ++ii) {
            #pragma unroll
            for (int j = 0; j < 4; ++j)
                #pragma unroll
                for (int reg = 0; reg < 4; ++reg)
                    ep[(ii * 16 + lq * 4 + reg) * 132 + wc * 64 + j * 16 + lr] =
                        acc[ibase + ii][j][reg];
        }
    }
}

// K0: z<BATCH: xT16[b][n][c] + x16[b][c][n] from x. z==BATCH: weights fp32->bf16.
__global__ __launch_bounds__(256) void k_prep(
    const float* __restrict__ x, const float* __restrict__ wA,
    const float* __restrict__ wB, const float* __restrict__ wV,
    unsigned short* __restrict__ xT, unsigned short* __restrict__ x16,
    unsigned short* __restrict__ wA16, unsigned short* __restrict__ wB16,
    unsigned short* __restrict__ wV16)
{
    if (blockIdx.z == BATCH) {
        int bl = blockIdx.y * 64 + blockIdx.x;
        if (bl >= 384) return;
        int e = (bl * 256 + threadIdx.x) * 4;
        const float* src; unsigned short* dst; int off;
        if (e < 262144)       { src = wA; dst = wA16; off = e; }
        else if (e < 327680)  { src = wB; dst = wB16; off = e - 262144; }
        else                  { src = wV; dst = wV16; off = e - 327680; }
        float4 v = *(const float4*)&src[off];
        *(ushort4*)&dst[off] = make_ushort4(f2b(v.x), f2b(v.y), f2b(v.z), f2b(v.w));
        return;
    }
    __shared__ unsigned short tile[64][68];
    int n0 = blockIdx.x * 64, c0 = blockIdx.y * 64, b = blockIdx.z;
    int t = threadIdx.x;
    int tr = t >> 4, tc4 = (t & 15) * 4;
    const float* xb = x + ((size_t)b * INC + c0) * NPIX + n0;
    unsigned short* x16p = x16 + ((size_t)b * INC + c0) * NPIX + n0;
    #pragma unroll
    for (int p = 0; p < 4; ++p) {
        int r = p * 16 + tr;
        float4 v = *(const float4*)&xb[(size_t)r * NPIX + tc4];
        ushort4 u = make_ushort4(f2b(v.x), f2b(v.y), f2b(v.z), f2b(v.w));
        *(ushort4*)&x16p[(size_t)r * NPIX + tc4] = u;
        tile[r][tc4 + 0] = u.x; tile[r][tc4 + 1] = u.y;
        tile[r][tc4 + 2] = u.z; tile[r][tc4 + 3] = u.w;
    }
    __syncthreads();
    unsigned short* o = xT + ((size_t)b * NPIX + n0) * INC + c0;
    #pragma unroll
    for (int p = 0; p < 4; ++p) {
        int n = p * 16 + tr;
        ushort4 u = make_ushort4(tile[tc4 + 0][n], tile[tc4 + 1][n],
                                 tile[tc4 + 2][n], tile[tc4 + 3][n]);
        *(ushort4*)&o[(size_t)n * INC + tc4] = u;
    }
}

// K1: Bf16/V16 [b][k][n] = bf16(W @ x + bias).  grid (NPIX/128, B*2)
__global__ __launch_bounds__(256) void k_proj(
    const unsigned short* __restrict__ xT, const unsigned short* __restrict__ wB16,
    const unsigned short* __restrict__ wV16, const float* __restrict__ bB,
    const float* __restrict__ bV, unsigned short* __restrict__ Bf16,
    unsigned short* __restrict__ V16)
{
    __shared__ __align__(16) char smem[32 * 132 * 4];
    unsigned short* lA = (unsigned short*)smem;
    unsigned short* lB = lA + 4096;
    int t = threadIdx.x;
    int n0 = blockIdx.x * 128;
    int z = blockIdx.y, b = z >> 1, br = z & 1;
    const unsigned short* A = br ? wV16 : wB16;
    const float* bias = br ? bV : bB;
    unsigned short* out = br ? V16 : Bf16;
    const unsigned short* Bm = xT + ((size_t)b * NPIX + n0) * INC;

    ZERO_ACC(acc);
    int lane = t & 63, w = t >> 6, wr = w >> 1, wc = w & 1;

    for (int c = 0; c < INC; c += 32) {
        stage_tile(A, INC, c, lA, t);
        stage_tile(Bm, INC, c, lB, t);
        __syncthreads();
        bt_compute(lA, lB, acc, wr, wc, lane);
        __syncthreads();
    }
    float* ep = (float*)smem;
    #pragma unroll
    for (int ch = 0; ch < 4; ++ch) {
        __syncthreads();
        ep_stage(ep, acc, ch, wr, wc, lane);
        __syncthreads();
        int r = t >> 3, c4 = (t & 7) * 16;
        int k = ch * 32 + r;
        float bv_ = bias[k];
        unsigned short* op = out + ((size_t)b * CN + k) * NPIX + n0 + c4;
        #pragma unroll
        for (int h = 0; h < 2; ++h) {
            us8v o;
            #pragma unroll
            for (int j = 0; j < 8; ++j) o[j] = f2b(ep[r * 132 + c4 + h * 8 + j] + bv_);
            *(us8v*)&op[h * 8] = o;
        }
    }
}

// K2: sB[b][k][n] = softmax over n.  grid (B*CN), 256 thr.
__global__ __launch_bounds__(256) void k_softmax_rows(
    const unsigned short* __restrict__ Bf16, unsigned short* __restrict__ sB)
{
    __shared__ float red[8];
    int row = blockIdx.x, t = threadIdx.x;
    const unsigned short* p = Bf16 + (size_t)row * NPIX + t * 16;
    us8v u0 = *(const us8v*)p, u1 = *(const us8v*)(p + 8);
    float v[16];
    #pragma unroll
    for (int j = 0; j < 8; ++j) { v[j] = b2f(u0[j]); v[8 + j] = b2f(u1[j]); }
    float m = -1e30f;
    #pragma unroll
    for (int j = 0; j < 16; ++j) m = fmaxf(m, v[j]);
    for (int o = 32; o > 0; o >>= 1) m = fmaxf(m, __shfl_xor(m, o));
    if ((t & 63) == 0) red[t >> 6] = m;
    __syncthreads();
    m = fmaxf(fmaxf(red[0], red[1]), fmaxf(red[2], red[3]));
    float s = 0.f;
    #pragma unroll
    for (int j = 0; j < 16; ++j) { v[j] = __expf(v[j] - m); s += v[j]; }
    for (int o = 32; o > 0; o >>= 1) s += __shfl_xor(s, o);
    if ((t & 63) == 0) red[4 + (t >> 6)] = s;
    __syncthreads();
    float r = 1.0f / (red[4] + red[5] + red[6] + red[7]);
    us8v o0, o1;
    #pragma unroll
    for (int j = 0; j < 8; ++j) { o0[j] = f2b(v[j] * r); o1[j] = f2b(v[8 + j] * r); }
    unsigned short* q = sB + (size_t)row * NPIX + t * 16;
    *(us8v*)q = o0; *(us8v*)(q + 8) = o1;
}

// K3: sVt[b][n][k] = softmax over k of V16[b][k][n], transposed. grid (NPIX/128, B)
__global__ __launch_bounds__(256) void k_softmax_cols(
    const unsigned short* __restrict__ V16, unsigned short* __restrict__ sVt)
{
    __shared__ unsigned short tv[128][138];
    __shared__ float pm[2][128], ps[2][128], sm[128], sr[128];
    int n0 = blockIdx.x * 128, b = blockIdx.y, t = threadIdx.x;
    const unsigned short* vb = V16 + (size_t)b * CN * NPIX + n0;
    #pragma unroll
    for (int it = 0; it < 8; ++it) {
        int f = it * 256 + t, k = f >> 4, n8 = (f & 15) * 8;
        us8v u = *(const us8v*)&vb[(size_t)k * NPIX + n8];
        #pragma unroll
        for (int j = 0; j < 8; ++j) tv[n8 + j][k] = u[j];
    }
    __syncthreads();
    {
        int p = t & 127, h = t >> 7;
        float m = -1e30f;
        for (int k = h * 64; k < h * 64 + 64; ++k) m = fmaxf(m, b2f(tv[p][k]));
        float s = 0.f;
        for (int k = h * 64; k < h * 64 + 64; ++k) s += __expf(b2f(tv[p][k]) - m);
        pm[h][p] = m; ps[h][p] = s;
    }
    __syncthreads();
    if (t < 128) {
        float ma = pm[0][t], mb = pm[1][t];
        float m = fmaxf(ma, mb);
        float s = ps[0][t] * __expf(ma - m) + ps[1][t] * __expf(mb - m);
        sm[t] = m; sr[t] = 1.0f / s;
    }
    __syncthreads();
    unsigned short* ob = sVt + ((size_t)b * NPIX + n0) * CN;
    #pragma unroll
    for (int it = 0; it < 8; ++it) {
        int idx = it * 2048 + t * 8, nl = idx >> 7, k0 = idx & 127;
        float m = sm[nl], r = sr[nl];
        us8v o;
        #pragma unroll
        for (int j = 0; j < 8; ++j) o[j] = f2b(__expf(b2f(tv[nl][k0 + j]) - m) * r);
        *(us8v*)&ob[(size_t)nl * CN + k0] = o;
    }
}

// K4: Pts[s][b][k][c] = sum_{n in split s} sB[k][n] * x16[c][n].  grid (INC/128, NSPLIT, B)
__global__ __launch_bounds__(256) void k_gather(
    const unsigned short* __restrict__ x16, const unsigned short* __restrict__ sB,
    float* __restrict__ Pts)
{
    __shared__ __align__(16) char smem[32 * 132 * 4];
    unsigned short* lA = (unsigned short*)smem;
    unsigned short* lB = lA + 4096;
    int t = threadIdx.x;
    int c0 = blockIdx.x * 128, s = blockIdx.y, b = blockIdx.z;
    const unsigned short* A = sB + (size_t)b * CN * NPIX;
    const unsigned short* Bm = x16 + ((size_t)b * INC + c0) * NPIX;
    int nbase = s * (NPIX / NSPLIT);

    ZERO_ACC(acc);
    int lane = t & 63, w = t >> 6, wr = w >> 1, wc = w & 1;

    for (int it = 0; it < (NPIX / NSPLIT) / 32; ++it) {
        int nb = nbase + it * 32;
        stage_tile(A, NPIX, nb, lA, t);
        stage_tile(Bm, NPIX, nb, lB, t);
        __syncthreads();
        bt_compute(lA, lB, acc, wr, wc, lane);
        __syncthreads();
    }
    float* ep = (float*)smem;
    #pragma unroll
    for (int ch = 0; ch < 4; ++ch) {
        __syncthreads();
        ep_stage(ep, acc, ch, wr, wc, lane);
        __syncthreads();
        int r = t >> 3, c4 = (t & 7) * 16;
        int k = ch * 32 + r;
        float* op = &Pts[(((size_t)s * BATCH + b) * CN + k) * INC + c0 + c4];
        #pragma unroll
        for (int q = 0; q < 4; ++q)
            *(float4*)&op[q * 4] = *(float4*)&ep[r * 132 + c4 + q * 4];
    }
}

// K5: Pt16[b][k][c] = bf16(sum_s Pts).  grid 512, 256 thr.
__global__ __launch_bounds__(256) void k_reduceP(
    const float* __restrict__ Pts, unsigned short* __restrict__ Pt16)
{
    int base = (blockIdx.x * 256 + threadIdx.x) * 4;
    float4 sacc = make_float4(0.f, 0.f, 0.f, 0.f);
    #pragma unroll
    for (int sp = 0; sp < NSPLIT; ++sp) {
        float4 v = *(const float4*)&Pts[(size_t)sp * (BATCH * CN * INC) + base];
        sacc.x += v.x; sacc.y += v.y; sacc.z += v.z; sacc.w += v.w;
    }
    *(ushort4*)&Pt16[base] = make_ushort4(f2b(sacc.x), f2b(sacc.y), f2b(sacc.z), f2b(sacc.w));
}

// K6: G16[b][m][k] = bf16(wA @ P + bA).  grid (CM/128, B)
__global__ __launch_bounds__(256) void k_G(
    const unsigned short* __restrict__ wA16, const float* __restrict__ bA,
    const unsigned short* __restrict__ Pt16, unsigned short* __restrict__ G16)
{
    __shared__ __align__(16) char smem[32 * 132 * 4];
    unsigned short* lA = (unsigned short*)smem;
    unsigned short* lB = lA + 4096;
    int t = threadIdx.x;
    int m0 = blockIdx.x * 128, b = blockIdx.y;
    const unsigned short* A = wA16 + (size_t)m0 * INC;
    const unsigned short* Bm = Pt16 + (size_t)b * CN * INC;

    ZERO_ACC(acc);
    int lane = t & 63, w = t >> 6, wr = w >> 1, wc = w & 1;

    for (int c = 0; c < INC; c += 32) {
        stage_tile(A, INC, c, lA, t);
        stage_tile(Bm, INC, c, lB, t);
        __syncthreads();
        bt_compute(lA, lB, acc, wr, wc, lane);
        __syncthreads();
    }
    float* ep = (float*)smem;
    #pragma unroll
    for (int ch = 0; ch < 4; ++ch) {
        __syncthreads();
        ep_stage(ep, acc, ch, wr, wc, lane);
        __syncthreads();
        int r = t >> 3, c4 = (t & 7) * 16;
        int m = m0 + ch * 32 + r;
        float bv_ = bA[m];
        unsigned short* op = G16 + ((size_t)b * CM + m) * CN + c4;
        #pragma unroll
        for (int h = 0; h < 2; ++h) {
            us8v o;
            #pragma unroll
            for (int j = 0; j < 8; ++j) o[j] = f2b(ep[r * 132 + c4 + h * 8 + j] + bv_);
            *(us8v*)&op[h * 8] = o;
        }
    }
}

// K7: out[b][m][n] = G @ sV + y.  grid (NPIX/128, CM/128, B)
__global__ __launch_bounds__(256) void k_Z(
    const unsigned short* __restrict__ G16, const unsigned short* __restrict__ sVt,
    const float* __restrict__ y, float* __restrict__ out)
{
    __shared__ __align__(16) char smem[32 * 132 * 4];
    unsigned short* lA = (unsigned short*)smem;
    unsigned short* lB = lA + 4096;
    int t = threadIdx.x;
    int n0 = blockIdx.x * 128, m0 = blockIdx.y * 128, b = blockIdx.z;
    const unsigned short* A = G16 + ((size_t)b * CM + m0) * CN;
    const unsigned short* Bm = sVt + ((size_t)b * NPIX + n0) * CN;

    ZERO_ACC(acc);
    int lane = t & 63, w = t >> 6, wr = w >> 1, wc = w & 1;

    for (int kc = 0; kc < CN; kc += 32) {
        stage_tile(A, CN, kc, lA, t);
        stage_tile(Bm, CN, kc, lB, t);
        __syncthreads();
        bt_compute(lA, lB, acc, wr, wc, lane);
        __syncthreads();
    }
    float* ep = (float*)smem;
    #pragma unroll
    for (int ch = 0; ch < 4; ++ch) {
        __syncthreads();
        ep_stage(ep, acc, ch, wr, wc, lane);
        __syncthreads();
        int r = t >> 3, c4 = (t & 7) * 16;
        int m = m0 + ch * 32 + r;
        size_t base = ((size_t)b * CM + m) * NPIX + n0 + c4;
        #pragma unroll
        for (int q = 0; q < 4; ++q) {
            float4 a = *(float4*)&ep[r * 132 + c4 + q * 4];
            float4 yv = *(const float4*)&y[base + q * 4];
            a.x += yv.x; a.y += yv.y; a.z += yv.z; a.w += yv.w;
            *(float4*)&out[base + q * 4] = a;
        }
    }
}

extern "C" void kernel_launch(void* const* d_in, const int* in_sizes, int n_in,
                              void* d_out, int out_size, void* d_ws, size_t ws_size,
                              hipStream_t stream)
{
    const float* x  = (const float*)d_in[0];
    const float* y  = (const float*)d_in[1];
    const float* wA = (const float*)d_in[2];
    const float* bA = (const float*)d_in[3];
    const float* wB = (const float*)d_in[4];
    const float* bB = (const float*)d_in[5];
    const float* wV = (const float*)d_in[6];
    const float* bV = (const float*)d_in[7];
    float* out = (float*)d_out;

    unsigned short* xT16 = (unsigned short*)d_ws;            // 16,777,216
    unsigned short* x16  = xT16 + 16777216;                  // 16,777,216
    unsigned short* wA16 = x16  + 16777216;                  // 262,144
    unsigned short* wB16 = wA16 + 262144;                    // 65,536
    unsigned short* wV16 = wB16 + 65536;                     // 65,536
    unsigned short* Bf16 = wV16 + 65536;                     // 4,194,304
    unsigned short* V16  = Bf16 + 4194304;                   // 4,194,304
    unsigned short* sB   = V16  + 4194304;                   // 4,194,304
    unsigned short* sVt  = sB   + 4194304;                   // 4,194,304
    unsigned short* Pt16 = sVt  + 4194304;                   // 524,288
    float*  Pts = (float*)(Pt16 + 524288);                   // 8*8*128*512 f32
    unsigned short* G16  = (unsigned short*)(Pts + (size_t)NSPLIT * BATCH * CN * INC);

    k_prep<<<dim3(64, 8, BATCH + 1), 256, 0, stream>>>(
        x, wA, wB, wV, xT16, x16, wA16, wB16, wV16);
    k_proj<<<dim3(NPIX / 128, BATCH * 2), 256, 0, stream>>>(
        xT16, wB16, wV16, bB, bV, Bf16, V16);
    k_softmax_rows<<<dim3(BATCH * CN), 256, 0, stream>>>(Bf16, sB);
    k_softmax_cols<<<dim3(NPIX / 128, BATCH), 256, 0, stream>>>(V16, sVt);
    k_gather<<<dim3(INC / 128, NSPLIT, BATCH), 256, 0, stream>>>(x16, sB, Pts);
    k_reduceP<<<512, 256, 0, stream>>>(Pts, Pt16);
    k_G<<<dim3(CM / 128, BATCH), 256, 0, stream>>>(wA16, bA, Pt16, G16);
    k_Z<<<dim3(NPIX / 128, CM / 128, BATCH), 256, 0, stream>>>(G16, sVt, y, out);
}